// Round 6
// baseline (1321.478 us; speedup 1.0000x reference)
//
#include <hip/hip_runtime.h>

// Problem constants
constexpr int Bsz = 2, Tsz = 512, Csz = 1024, Hsz = 16, Dsz = 64, CSz = 64;
constexpr int NCHUNK = 8, OW = 8;
constexpr int BP = 72;    // pitch for GEMM staging planes (f16)

// Polar Express quintic coefficients (first NS_STEPS=5 rows)
__constant__ float PE_A[5] = {8.28721201814563f, 4.107059111542203f, 3.9486908534822946f,
                              3.3184196573706015f, 2.300652019954817f};
__constant__ float PE_B[5] = {-23.595886519098837f, -2.9478499167379106f, -2.908902115962949f,
                              -2.488488024314874f, -1.6689039845747493f};
__constant__ float PE_C[5] = {17.300387312530933f, 0.5448431082926601f, 0.5518191394370137f,
                              0.51004894012372f, 0.4188073119525673f};

typedef __attribute__((ext_vector_type(8))) _Float16 half8;
typedef __attribute__((ext_vector_type(4))) _Float16 half4;
typedef __attribute__((ext_vector_type(16))) float f32x16;

constexpr float INV_S = 1.0f / 2048.0f;

struct HL { _Float16 h, l; };

// fp32 v ~= hi + (lo/2048); hi/lo f16 RN; lo pre-scaled into normal range.
__device__ __forceinline__ HL split_f16(float v) {
  HL o;
  o.h = (_Float16)v;                 // RN
  float r = v - (float)o.h;          // exact residual
  o.l = (_Float16)(r * 2048.0f);
  return o;
}

#define MFMA2(accH, accL, ah, al, bh, bl)                                     \
  accH = __builtin_amdgcn_mfma_f32_32x32x16_f16(ah, bh, accH, 0, 0, 0);       \
  accL = __builtin_amdgcn_mfma_f32_32x32x16_f16(ah, bl, accL, 0, 0, 0);       \
  accL = __builtin_amdgcn_mfma_f32_32x32x16_f16(al, bh, accL, 0, 0, 0);

// fragment read from a pitch-BP (unswizzled) plane: row = rowbase+(lane&31),
// cols 16*ks + 8*(lane>>5) .. +7
__device__ __forceinline__ half8 ldfragp(const _Float16* P, int rowbase, int ks, int lane) {
  int row = rowbase + (lane & 31);
  int col = (ks << 4) + ((lane >> 5) << 3);
  return *(const half8*)&P[row * BP + col];
}

// ---------------------------------------------------------------------------
// Split-f16 MFMA GEMM: O[m][n] = sum_k A[m][k] * W[n][k]  (A @ W.T), fp32 I/O.
// 64x64 block tile, 256 threads / 4 waves, each wave one 32x32 MFMA tile.
// ---------------------------------------------------------------------------
__global__ __launch_bounds__(256) void gemm_nt_mfma(const float* __restrict__ A,
                                                    const float* __restrict__ W,
                                                    float* __restrict__ O,
                                                    int M, int N, int K) {
  __shared__ __attribute__((aligned(16))) _Float16 Ah[64 * BP], Al[64 * BP];
  __shared__ __attribute__((aligned(16))) _Float16 Wh[64 * BP], Wl[64 * BP];
  const int tid = threadIdx.x;
  const int lane = tid & 63, wv = tid >> 6;
  const int m0 = blockIdx.x * 64, n0 = blockIdx.y * 64;
  const int mb = (wv >> 1) << 5, nb = (wv & 1) << 5;
  const int crow = ((lane >> 5) << 2), ccol = lane & 31;
  const int sr = tid >> 4, sc = (tid & 15) << 2;

  f32x16 accH, accL;
#pragma unroll
  for (int r = 0; r < 16; ++r) { accH[r] = 0.f; accL[r] = 0.f; }

  for (int k0 = 0; k0 < K; k0 += 64) {
    __syncthreads();
#pragma unroll
    for (int i = 0; i < 4; ++i) {
      int row = sr + i * 16;
      float4 av = *(const float4*)(A + (size_t)(m0 + row) * K + k0 + sc);
      float4 wv4 = *(const float4*)(W + (size_t)(n0 + row) * K + k0 + sc);
      half4 ahv, alv, whv, wlv;
      HL s;
      s = split_f16(av.x);  ahv[0] = s.h; alv[0] = s.l;
      s = split_f16(av.y);  ahv[1] = s.h; alv[1] = s.l;
      s = split_f16(av.z);  ahv[2] = s.h; alv[2] = s.l;
      s = split_f16(av.w);  ahv[3] = s.h; alv[3] = s.l;
      s = split_f16(wv4.x); whv[0] = s.h; wlv[0] = s.l;
      s = split_f16(wv4.y); whv[1] = s.h; wlv[1] = s.l;
      s = split_f16(wv4.z); whv[2] = s.h; wlv[2] = s.l;
      s = split_f16(wv4.w); whv[3] = s.h; wlv[3] = s.l;
      *(half4*)&Ah[row * BP + sc] = ahv; *(half4*)&Al[row * BP + sc] = alv;
      *(half4*)&Wh[row * BP + sc] = whv; *(half4*)&Wl[row * BP + sc] = wlv;
    }
    __syncthreads();
#pragma unroll
    for (int ks = 0; ks < 4; ++ks) {
      half8 ah = ldfragp(Ah, mb, ks, lane), al = ldfragp(Al, mb, ks, lane);
      half8 bh = ldfragp(Wh, nb, ks, lane), bl = ldfragp(Wl, nb, ks, lane);
      MFMA2(accH, accL, ah, al, bh, bl);
    }
  }
#pragma unroll
  for (int r = 0; r < 16; ++r) {
    int rr = mb + crow + (r & 3) + ((r >> 2) << 3);
    int cc2 = nb + ccol;
    O[(size_t)(m0 + rr) * N + n0 + cc2] = accH[r] + accL[r] * INV_S;
  }
}

// ---------------------------------------------------------------------------
// Gates
// ---------------------------------------------------------------------------
__global__ __launch_bounds__(64) void gates_kernel(const float* __restrict__ x,
                                                   const float* __restrict__ Wa,
                                                   const float* __restrict__ We,
                                                   const float* __restrict__ Wt,
                                                   const float* __restrict__ Wg,
                                                   float* __restrict__ ga, float* __restrict__ ge,
                                                   float* __restrict__ gt, float* __restrict__ gg) {
  __shared__ float xs[Csz];
  const int bt = blockIdx.x;
  const int tid = threadIdx.x;
  const float* xr = x + (size_t)bt * Csz;
  for (int i = tid * 4; i < Csz; i += 64 * 4) *(float4*)&xs[i] = *(const float4*)&xr[i];
  __syncthreads();
  const int gsel = tid >> 4, h = tid & 15;
  const float* Wrow = (gsel == 0 ? Wa : gsel == 1 ? We : gsel == 2 ? Wt : Wg) + (size_t)h * Csz;
  float acc = 0.f;
  for (int i = 0; i < Csz; i += 4) {
    float4 w4 = *(const float4*)&Wrow[i];
    acc += xs[i] * w4.x + xs[i + 1] * w4.y + xs[i + 2] * w4.z + xs[i + 3] * w4.w;
  }
  float s = 1.f / (1.f + expf(-acc));
  float* outp = (gsel == 0 ? ga : gsel == 1 ? ge : gsel == 2 ? gt : gg);
  outp[(size_t)bt * Hsz + h] = s;
}

// ---------------------------------------------------------------------------
// Causal depthwise conv (K=4) + optional rms_norm/poly
// ---------------------------------------------------------------------------
__global__ __launch_bounds__(256) void conv_kernel(const float* __restrict__ lin,
                                                   const float* __restrict__ w,
                                                   const float* __restrict__ bias,
                                                   float* __restrict__ out, int do_norm) {
  const int bt = blockIdx.x;
  const int b = bt >> 9, t = bt & 511;
  const int tid = threadIdx.x;
  const int c0 = tid << 2;
  float4 bv = *(const float4*)&bias[c0];
  float v0 = bv.x, v1 = bv.y, v2 = bv.z, v3 = bv.w;
  float4 w0 = *(const float4*)&w[(c0 + 0) * 4];
  float4 w1 = *(const float4*)&w[(c0 + 1) * 4];
  float4 w2 = *(const float4*)&w[(c0 + 2) * 4];
  float4 w3 = *(const float4*)&w[(c0 + 3) * 4];
  const float* base = lin + (size_t)b * Tsz * Csz + c0;
#pragma unroll
  for (int j = 0; j < 4; ++j) {
    int tt = t - 3 + j;
    if (tt < 0) continue;
    float4 xv = *(const float4*)(base + (size_t)tt * Csz);
    v0 += xv.x * (&w0.x)[j];
    v1 += xv.y * (&w1.x)[j];
    v2 += xv.z * (&w2.x)[j];
    v3 += xv.w * (&w3.x)[j];
  }
  if (do_norm) {
    float ss = v0 * v0 + v1 * v1 + v2 * v2 + v3 * v3;
    ss += __shfl_xor(ss, 1, 16);
    ss += __shfl_xor(ss, 2, 16);
    ss += __shfl_xor(ss, 4, 16);
    ss += __shfl_xor(ss, 8, 16);
    float scl = rsqrtf(ss * (1.f / 64.f) + 1e-6f);
    v0 *= scl; v1 *= scl; v2 *= scl; v3 *= scl;
    v0 += 0.5f * v0 * v0; v1 += 0.5f * v1 * v1; v2 += 0.5f * v2 * v2; v3 += 0.5f * v3 * v3;
  }
  float4 o = {v0, v1, v2, v3};
  *(float4*)(out + (size_t)bt * Csz + c0) = o;
}

// ---------------------------------------------------------------------------
// rms_norm for y
// ---------------------------------------------------------------------------
__global__ __launch_bounds__(256) void rms_kernel(const float* __restrict__ in,
                                                  float* __restrict__ out) {
  const int bt = blockIdx.x;
  const int tid = threadIdx.x;
  const int c0 = tid << 2;
  float4 xv = *(const float4*)(in + (size_t)bt * Csz + c0);
  float ss = xv.x * xv.x + xv.y * xv.y + xv.z * xv.z + xv.w * xv.w;
  ss += __shfl_xor(ss, 1, 16);
  ss += __shfl_xor(ss, 2, 16);
  ss += __shfl_xor(ss, 4, 16);
  ss += __shfl_xor(ss, 8, 16);
  float scl = rsqrtf(ss * (1.f / 64.f) + 1e-6f);
  float4 o = {xv.x * scl, xv.y * scl, xv.z * scl, xv.w * scl};
  *(float4*)(out + (size_t)bt * Csz + c0) = o;
}

// ---------------------------------------------------------------------------
// B1+B2 fused: err = M k - v, then omega window + momentum scan.
// ---------------------------------------------------------------------------
__global__ __launch_bounds__(256) void mom_scan_kernel(const float* __restrict__ Mst,
                                                       const float* __restrict__ kp,
                                                       const float* __restrict__ vp,
                                                       const float* __restrict__ geta,
                                                       const float* __restrict__ gtheta,
                                                       const float* __restrict__ ggamma,
                                                       float* __restrict__ Sst,
                                                       float* __restrict__ chunkS, int ci) {
  __shared__ float Ml[4 * Dsz];
  __shared__ float errl[256];
  __shared__ float kkl[CSz * Dsz];
  __shared__ float gl[CSz], el[CSz], tl[CSz];
  const int blk = blockIdx.x;
  const int bh = blk >> 4, eb = blk & 15;
  const int b = bh >> 4, h = bh & 15;
  const int tid = threadIdx.x;
  Ml[tid & 255] = Mst[(size_t)bh * 4096 + eb * 4 * 64 + tid];
#pragma unroll
  for (int i = 0; i < 16; ++i) {
    int idx = i * 256 + tid;
    int t = idx >> 6, k = idx & 63;
    kkl[idx] = kp[(((size_t)b * Tsz + ci * CSz + t) * Hsz + h) * Dsz + k];
  }
  if (tid < CSz) {
    size_t gi = ((size_t)b * Tsz + ci * CSz + tid) * Hsz + h;
    gl[tid] = ggamma[gi];
    el[tid] = geta[gi];
    tl[tid] = gtheta[gi];
  }
  __syncthreads();
  {
    const int tt = tid >> 2, vl = tid & 3;
    float acc = 0.f;
#pragma unroll 8
    for (int k = 0; k < Dsz; ++k) acc += Ml[vl * 64 + k] * kkl[tt * 64 + k];
    float vv = vp[(((size_t)b * Tsz + ci * CSz + tt) * Hsz + h) * Dsz + eb * 4 + vl];
    errl[tt * 4 + vl] = acc - vv;
  }
  __syncthreads();
  const int e = eb * 256 + tid;
  const int vloc = tid >> 6;
  const int k = tid & 63;
  float S = Sst[(size_t)bh * 4096 + e];
  float ring[OW];
  float wsum = 0.f;
  float* outp = chunkS + (size_t)bh * CSz * 4096 + e;
#pragma unroll
  for (int t = 0; t < CSz; ++t) {
    float u = 2.f * errl[t * 4 + vloc] * kkl[t * 64 + k];
    float val = gl[t] * u;
    wsum += val;
    if (t >= OW) wsum -= ring[t & (OW - 1)];
    ring[t & (OW - 1)] = val;
    S = tl[t] * S - el[t] * wsum;
    outp[(size_t)t * 4096] = S;
  }
  Sst[(size_t)bh * 4096 + e] = S;
}

// ---------------------------------------------------------------------------
// B3: Polar Express via scaled split-f16 MFMA, XOR-swizzled pitch-64 planes.
// Element (r,c) of a plane lives at r*64 + ((c>>3)^(r&7))*8 + (c&7): zero
// padding (8 KB/plane), same bank spread as pitch-72. 6 planes = 48 KB ->
// 3 blocks/CU. A-planes are reused for Bm (extra barrier between read/write).
// ---------------------------------------------------------------------------
__device__ __forceinline__ int swz(int r, int c) {
  return (r << 6) + ((((c >> 3) ^ (r & 7)) << 3) | (c & 7));
}

// fragment read: row = rowbase+(lane&31), cols 16*ks+8*(lane>>5).. (+7)
__device__ __forceinline__ half8 ldfrag_s(const _Float16* P, int rowbase, int ks, int lane) {
  int row = rowbase + (lane & 31);
  int cb = (ks << 1) + (lane >> 5);          // col block index (c>>3)
  int off = (row << 6) + (((cb ^ (row & 7)) << 3));
  return *(const half8*)&P[off];
}

// Write this wave's 16 C-values transposed (for symmetric or transpose-target
// planes) as 4+4 ds_write_b64: row = nb+ccol, col block (mb+8g)>>3, inner crow.
__device__ __forceinline__ void store_sym_t(_Float16* Phi, _Float16* Plo,
                                            const float* vals16, int mb, int nb,
                                            int crow, int ccol) {
  int R = nb + ccol;
#pragma unroll
  for (int g = 0; g < 4; ++g) {
    half4 hv, lv;
#pragma unroll
    for (int j = 0; j < 4; ++j) {
      HL s = split_f16(vals16[g * 4 + j]);
      hv[j] = s.h; lv[j] = s.l;
    }
    int cb = ((mb + (g << 3)) >> 3);
    int off = (R << 6) + (((cb ^ (R & 7)) << 3) | crow);
    *(half4*)&Phi[off] = hv;
    *(half4*)&Plo[off] = lv;
  }
}

__global__ __launch_bounds__(256) void pe_mfma_kernel(float* __restrict__ chunkS) {
  __shared__ __attribute__((aligned(16))) _Float16 Xhi[4096];
  __shared__ __attribute__((aligned(16))) _Float16 Xlo[4096];
  __shared__ __attribute__((aligned(16))) _Float16 XThi[4096];
  __shared__ __attribute__((aligned(16))) _Float16 XTlo[4096];
  __shared__ __attribute__((aligned(16))) _Float16 Ahi[4096];   // reused for Bm
  __shared__ __attribute__((aligned(16))) _Float16 Alo[4096];
  __shared__ float red[4];
  const int tid = threadIdx.x;
  const int lane = tid & 63;
  const int wv = tid >> 6;
  float* G = chunkS + (size_t)blockIdx.x * 4096;

  // ---- load + Frobenius normalize ----
  float vals[16];
  float ss = 0.f;
#pragma unroll
  for (int i = 0; i < 16; ++i) {
    float xv = G[i * 256 + tid];
    vals[i] = xv;
    ss += xv * xv;
  }
#pragma unroll
  for (int off = 32; off; off >>= 1) ss += __shfl_xor(ss, off, 64);
  if (lane == 0) red[wv] = ss;
  __syncthreads();
  float tot = red[0] + red[1] + red[2] + red[3];
  float scale = 1.f / ((sqrtf(tot) + 1e-7f) * 1.01f);
#pragma unroll
  for (int i = 0; i < 16; ++i) {
    int idx = i * 256 + tid;
    int row = idx >> 6, col = idx & 63;
    HL s = split_f16(vals[i] * scale);
    Xhi[swz(row, col)] = s.h;  Xlo[swz(row, col)] = s.l;
    XThi[swz(col, row)] = s.h; XTlo[swz(col, row)] = s.l;
  }

  const int mb = (wv >> 1) << 5;        // tile row base
  const int nb = (wv & 1) << 5;         // tile col base
  const int crow = ((lane >> 5) << 2);  // C-frag: row = mb+crow+(r&3)+8*(r>>2)
  const int ccol = lane & 31;           // C-frag: col = nb+ccol

  for (int it = 0; it < 5; ++it) {
    const float ca = PE_A[it], cb = PE_B[it], cc = PE_C[it];
    __syncthreads();  // X/XT ready
    // ---- A = X X^T ----
    f32x16 accH, accL;
#pragma unroll
    for (int r = 0; r < 16; ++r) { accH[r] = 0.f; accL[r] = 0.f; }
#pragma unroll
    for (int ks = 0; ks < 4; ++ks) {
      half8 ah = ldfrag_s(Xhi, mb, ks, lane), al = ldfrag_s(Xlo, mb, ks, lane);
      half8 bh = ldfrag_s(Xhi, nb, ks, lane), bl = ldfrag_s(Xlo, nb, ks, lane);
      MFMA2(accH, accL, ah, al, bh, bl);
    }
    float Aval[16];
#pragma unroll
    for (int r = 0; r < 16; ++r) Aval[r] = accH[r] + accL[r] * INV_S;
    store_sym_t(Ahi, Alo, Aval, mb, nb, crow, ccol);
    __syncthreads();  // A complete
    // ---- A2 = A A (A symmetric) ----
    f32x16 acc2H, acc2L;
#pragma unroll
    for (int r = 0; r < 16; ++r) { acc2H[r] = 0.f; acc2L[r] = 0.f; }
#pragma unroll
    for (int ks = 0; ks < 4; ++ks) {
      half8 ah = ldfrag_s(Ahi, mb, ks, lane), al = ldfrag_s(Alo, mb, ks, lane);
      half8 bh = ldfrag_s(Ahi, nb, ks, lane), bl = ldfrag_s(Alo, nb, ks, lane);
      MFMA2(acc2H, acc2L, ah, al, bh, bl);
    }
    // ---- Bm = b A + c A2 + a I ----
    float Bval[16];
#pragma unroll
    for (int r = 0; r < 16; ++r) {
      int rr = mb + crow + (r & 3) + ((r >> 2) << 3);
      int cc2 = nb + ccol;
      float bm = cb * Aval[r] + cc * (acc2H[r] + acc2L[r] * INV_S);
      if (rr == cc2) bm += ca;
      Bval[r] = bm;
    }
    __syncthreads();  // all stage-2 reads of A done before overwrite
    store_sym_t(Ahi, Alo, Bval, mb, nb, crow, ccol);  // Bm into A planes
    __syncthreads();  // Bm complete
    // ---- X' = Bm X  (B-op: XT rows) ----
    f32x16 accXH, accXL;
#pragma unroll
    for (int r = 0; r < 16; ++r) { accXH[r] = 0.f; accXL[r] = 0.f; }
#pragma unroll
    for (int ks = 0; ks < 4; ++ks) {
      half8 ah = ldfrag_s(Ahi, mb, ks, lane), al = ldfrag_s(Alo, mb, ks, lane);
      half8 bh = ldfrag_s(XThi, nb, ks, lane), bl = ldfrag_s(XTlo, nb, ks, lane);
      MFMA2(accXH, accXL, ah, al, bh, bl);
    }
    if (it < 4) {
      __syncthreads();  // all stage-3 reads of X/XT done
      float Xval[16];
#pragma unroll
      for (int r = 0; r < 16; ++r) Xval[r] = accXH[r] + accXL[r] * INV_S;
      store_sym_t(XThi, XTlo, Xval, mb, nb, crow, ccol);  // XT: b64 writes
#pragma unroll
      for (int r = 0; r < 16; ++r) {                      // X: b16 scatter
        int rr = mb + crow + (r & 3) + ((r >> 2) << 3);
        int cc2 = nb + ccol;
        HL s = split_f16(Xval[r]);
        Xhi[swz(rr, cc2)] = s.h;  Xlo[swz(rr, cc2)] = s.l;
      }
    } else {
      // ---- final store (fp32, unswizzled global) ----
#pragma unroll
      for (int r = 0; r < 16; ++r) {
        int rr = mb + crow + (r & 3) + ((r >> 2) << 3);
        int cc2 = nb + ccol;
        G[rr * 64 + cc2] = accXH[r] + accXL[r] * INV_S;
      }
    }
  }
}

// ---------------------------------------------------------------------------
// B4: memory scan + read
// ---------------------------------------------------------------------------
__global__ __launch_bounds__(256) void mem_scan_kernel(const float* __restrict__ chunkS,
                                                       const float* __restrict__ qp,
                                                       const float* __restrict__ galpha,
                                                       float* __restrict__ Mst,
                                                       float* __restrict__ ybuf, int ci) {
  __shared__ float ql[CSz * Dsz];
  __shared__ float al[CSz];
  const int blk = blockIdx.x;
  const int bh = blk >> 4, eb = blk & 15;
  const int b = bh >> 4, h = bh & 15;
  const int tid = threadIdx.x;
  const int w = tid >> 6, lane = tid & 63;
  const int v = eb * 4 + w, k = lane;
  for (int i = tid; i < CSz * Dsz; i += 256) {
    int t = i >> 6, kk = i & 63;
    ql[i] = qp[(((size_t)b * Tsz + ci * CSz + t) * Hsz + h) * Dsz + kk];
  }
  if (tid < CSz) al[tid] = galpha[((size_t)b * Tsz + ci * CSz + tid) * Hsz + h];
  __syncthreads();
  float m = Mst[(size_t)bh * 4096 + v * 64 + k];
  const float* Xo = chunkS + (size_t)bh * CSz * 4096;
  for (int t = 0; t < CSz; ++t) {
    m = al[t] * m + Xo[(size_t)t * 4096 + v * 64 + k];
    float p = m * ql[t * 64 + k];
#pragma unroll
    for (int off = 32; off; off >>= 1) p += __shfl_xor(p, off, 64);
    if (lane == 0) ybuf[(((size_t)b * Tsz + ci * CSz + t) * Hsz + h) * Dsz + v] = p;
  }
  Mst[(size_t)bh * 4096 + v * 64 + k] = m;
}

// ---------------------------------------------------------------------------
extern "C" void kernel_launch(void* const* d_in, const int* in_sizes, int n_in,
                              void* d_out, int out_size, void* d_ws, size_t ws_size,
                              hipStream_t stream) {
  (void)in_sizes; (void)n_in; (void)out_size; (void)ws_size;
  const float* x   = (const float*)d_in[0];
  const float* Wq  = (const float*)d_in[1];
  const float* Wk  = (const float*)d_in[2];
  const float* Wv  = (const float*)d_in[3];
  const float* Wo  = (const float*)d_in[4];
  const float* cqw = (const float*)d_in[5];
  const float* cqb = (const float*)d_in[6];
  const float* ckw = (const float*)d_in[7];
  const float* ckb = (const float*)d_in[8];
  const float* cvw = (const float*)d_in[9];
  const float* cvb = (const float*)d_in[10];
  const float* Wa  = (const float*)d_in[11];
  const float* We  = (const float*)d_in[12];
  const float* Wt  = (const float*)d_in[13];
  const float* Wg  = (const float*)d_in[14];
  float* out = (float*)d_out;

  float* p = (float*)d_ws;
  const size_t NBTC = (size_t)Bsz * Tsz * Csz;
  const size_t NBTH = (size_t)Bsz * Tsz * Hsz;
  const size_t NMAT = (size_t)Bsz * Hsz * Dsz * Dsz;
  float* qlin = p; p += NBTC;
  float* klin = p; p += NBTC;
  float* vlin = p; p += NBTC;
  float* qp   = p; p += NBTC;
  float* kp   = p; p += NBTC;
  float* vp   = p; p += NBTC;
  float* ga   = p; p += NBTH;
  float* ge   = p; p += NBTH;
  float* gt   = p; p += NBTH;
  float* gg   = p; p += NBTH;
  float* Mst  = p; p += NMAT;
  float* Sst  = p; p += NMAT;
  float* chS  = p; p += (size_t)Bsz * Hsz * CSz * Dsz * Dsz;
  float* ybuf = p; p += NBTC;
  float* ynrm = p; p += NBTC;

  hipMemsetAsync(Mst, 0, NMAT * sizeof(float), stream);
  hipMemsetAsync(Sst, 0, NMAT * sizeof(float), stream);

  dim3 gg16(16, 16);
  gemm_nt_mfma<<<gg16, 256, 0, stream>>>(x, Wq, qlin, Bsz * Tsz, Csz, Csz);
  gemm_nt_mfma<<<gg16, 256, 0, stream>>>(x, Wk, klin, Bsz * Tsz, Csz, Csz);
  gemm_nt_mfma<<<gg16, 256, 0, stream>>>(x, Wv, vlin, Bsz * Tsz, Csz, Csz);
  gates_kernel<<<Bsz * Tsz, 64, 0, stream>>>(x, Wa, We, Wt, Wg, ga, ge, gt, gg);
  conv_kernel<<<Bsz * Tsz, 256, 0, stream>>>(qlin, cqw, cqb, qp, 1);
  conv_kernel<<<Bsz * Tsz, 256, 0, stream>>>(klin, ckw, ckb, kp, 1);
  conv_kernel<<<Bsz * Tsz, 256, 0, stream>>>(vlin, cvw, cvb, vp, 0);

  for (int ci = 0; ci < NCHUNK; ++ci) {
    mom_scan_kernel<<<Bsz * Hsz * 16, 256, 0, stream>>>(Mst, kp, vp, ge, gt, gg, Sst, chS, ci);
    pe_mfma_kernel<<<Bsz * Hsz * CSz, 256, 0, stream>>>(chS);
    mem_scan_kernel<<<Bsz * Hsz * 16, 256, 0, stream>>>(chS, qp, ga, Mst, ybuf, ci);
  }

  rms_kernel<<<Bsz * Tsz, 256, 0, stream>>>(ybuf, ynrm);
  gemm_nt_mfma<<<gg16, 256, 0, stream>>>(ynrm, Wo, out, Bsz * Tsz, Csz, Csz);
}